// Round 1
// baseline (217.340 us; speedup 1.0000x reference)
//
#include <hip/hip_runtime.h>

// YOLO loss, 3 levels. Inputs (fp32):
//   d_in[0..2] = pred0/1/2  (N=16, C=255, H, W), H=W in {52,26,13}
//   d_in[3..5] = label0/1/2 (N, H, W, 3, 85)
// Output: d_out = [reg, conf, prob] fp32.
//
// Strategy: label_conf is ~0.08% ones -> xy/wh/prob losses only at positive
// cells. top_k(64) over 0/1 conf + valid-mask == "all positive boxes of the
// image" (counts << 64). Two kernels: (A) compact positive boxes per
// (level,image) into workspace; (B) per-cell conf loss + IoU ignore mask +
// rare positive-cell branch; block-reduce -> atomics.

#define LVLS 3
#define NIMG 16
#define MAXB 64

// per-level cell counts (cell = (n, a, h, w)): N*3*H*W
#define C0 (16 * 3 * 52 * 52)   // 129792
#define C1 (16 * 3 * 26 * 26)   // 32448
#define C2 (16 * 3 * 13 * 13)   // 8112
#define CTOT (C0 + C1 + C2)     // 170352

__device__ __constant__ float d_anchors[3][3][2] = {
    {{12.f, 16.f}, {19.f, 36.f}, {40.f, 28.f}},
    {{36.f, 75.f}, {76.f, 55.f}, {72.f, 146.f}},
    {{142.f, 110.f}, {192.f, 243.f}, {459.f, 401.f}}};

__device__ __forceinline__ float bce_logits(float x, float t) {
    return fmaxf(x, 0.f) - x * t + log1pf(expf(-fabsf(x)));
}

// ---------------- Kernel A: compact positive boxes ----------------
// cell index here is in label-record order: cell = ((n*H+h)*W+w)*3 + a,
// so lab + cell*85 is one contiguous 85-float record; n = cell / (3*H*W).
__global__ void collect_pos(const float* __restrict__ l0,
                            const float* __restrict__ l1,
                            const float* __restrict__ l2,
                            int* __restrict__ counts,
                            float4* __restrict__ boxes) {
    int gid = blockIdx.x * blockDim.x + threadIdx.x;
    const float* lab;
    int level, cell, hw3;
    if (gid < C0)            { level = 0; cell = gid;           lab = l0; hw3 = 3 * 52 * 52; }
    else if (gid < C0 + C1)  { level = 1; cell = gid - C0;      lab = l1; hw3 = 3 * 26 * 26; }
    else if (gid < CTOT)     { level = 2; cell = gid - C0 - C1; lab = l2; hw3 = 3 * 13 * 13; }
    else return;

    const float* lp = lab + (size_t)cell * 85;
    float lconf = lp[4];
    if (lconf > 0.f) {
        int n = cell / hw3;
        int p = atomicAdd(&counts[level * NIMG + n], 1);
        if (p < MAXB) {
            float4 b;
            b.x = lp[0]; b.y = lp[1]; b.z = lp[2]; b.w = lp[3];
            boxes[(level * NIMG + n) * MAXB + p] = b;
        }
    }
}

// ---------------- Kernel B: main loss ----------------
// cell index in feature-friendly order: cell = ((n*3+a)*H + h)*W + w
//   -> hw = cell % HW, a = (cell/HW) % 3, n = cell/(3*HW)
// feature element (n, a*85+j, h, w) = f[n*255*HW + (a*85+j)*HW + hw]
// label record = lab[((n*HW + hw)*3 + a)*85 + j]
__global__ void yolo_loss(const float* __restrict__ f0,
                          const float* __restrict__ f1,
                          const float* __restrict__ f2,
                          const float* __restrict__ l0,
                          const float* __restrict__ l1,
                          const float* __restrict__ l2,
                          const int* __restrict__ counts,
                          const float4* __restrict__ boxes,
                          float* __restrict__ out) {
    int gid = blockIdx.x * blockDim.x + threadIdx.x;

    float reg = 0.f, conf = 0.f, prob = 0.f;

    if (gid < CTOT) {
        const float *f, *lab;
        int level, cell, W, HW;
        float stride;
        if (gid < C0)           { level = 0; cell = gid;           f = f0; lab = l0; W = 52; HW = 52 * 52; stride = 8.f; }
        else if (gid < C0 + C1) { level = 1; cell = gid - C0;      f = f1; lab = l1; W = 26; HW = 26 * 26; stride = 16.f; }
        else                    { level = 2; cell = gid - C0 - C1; f = f2; lab = l2; W = 13; HW = 13 * 13; stride = 32.f; }

        int hw = cell % HW;
        int na = cell / HW;
        int a = na % 3;
        int n = na / 3;
        int w = hw % W;
        int h = hw / W;

        const float* fp = f + (size_t)n * 255 * HW + (size_t)a * 85 * HW + hw;
        const float* lp = lab + ((size_t)(n * HW + hw) * 3 + a) * 85;

        float rx = fp[0];
        float ry = fp[HW];
        float rw = fp[2 * HW];
        float rh = fp[3 * HW];
        float rc = fp[4 * HW];
        float lconf = lp[4];

        float aw = d_anchors[level][a][0];
        float ah = d_anchors[level][a][1];

        // pred box (pixel coords)
        float px = (1.f / (1.f + expf(-rx)) + (float)w) * stride;
        float py = (1.f / (1.f + expf(-ry)) + (float)h) * stride;
        float pw = expf(rw) * aw;
        float ph = expf(rh) * ah;

        // max IoU over this image's positive boxes
        int m = counts[level * NIMG + n];
        if (m > MAXB) m = MAXB;
        const float4* bl = boxes + (level * NIMG + n) * MAXB;
        float parea = pw * ph;
        float pl = px - pw * 0.5f, pr = px + pw * 0.5f;
        float pt = py - ph * 0.5f, pb = py + ph * 0.5f;
        float maxiou = 0.f;
        for (int i = 0; i < m; ++i) {
            float4 b = bl[i];
            float tl = b.x - b.z * 0.5f, tr = b.x + b.z * 0.5f;
            float tt = b.y - b.w * 0.5f, tb = b.y + b.w * 0.5f;
            float iw = fminf(pr, tr) - fmaxf(pl, tl);
            float ih = fminf(pb, tb) - fmaxf(pt, tt);
            iw = fmaxf(iw, 0.f);
            ih = fmaxf(ih, 0.f);
            float inter = iw * ih;
            float uni = parea + b.z * b.w - inter;
            float iou = inter / fmaxf(uni, 1e-9f);
            maxiou = fmaxf(maxiou, iou);
        }

        float bce_c = bce_logits(rc, lconf);
        float ign = (maxiou < 0.5f) ? 1.f : 0.f;
        conf = (lconf + (1.f - lconf) * ign) * bce_c;

        if (lconf > 0.f) {
            float lx = lp[0], ly = lp[1], lw = lp[2], lh = lp[3];
            float ox = lx / stride - (float)w;
            float oy = ly / stride - (float)h;
            float ow = logf(lw / aw + 1e-7f);
            float oh = logf(lh / ah + 1e-7f);
            float scale = 2.f - lw * lh * (1.f / (416.f * 416.f));
            float xyl = scale * (bce_logits(rx, ox) + bce_logits(ry, oy));
            float dw = rw - ow, dh = rh - oh;
            float whl = scale * 0.5f * (dw * dw + dh * dh);
            reg = xyl + whl;

            float p = 0.f;
            for (int j = 0; j < 80; ++j)
                p += bce_logits(fp[(5 + j) * HW], lp[5 + j]);
            prob = p;
        }
    }

    // wave (64) reduce, then block reduce across 4 waves, then atomics
    for (int off = 32; off > 0; off >>= 1) {
        reg += __shfl_down(reg, off);
        conf += __shfl_down(conf, off);
        prob += __shfl_down(prob, off);
    }
    __shared__ float s[3][4];
    int lane = threadIdx.x & 63;
    int wid = threadIdx.x >> 6;
    if (lane == 0) { s[0][wid] = reg; s[1][wid] = conf; s[2][wid] = prob; }
    __syncthreads();
    if (threadIdx.x == 0) {
        float r = s[0][0] + s[0][1] + s[0][2] + s[0][3];
        float c = s[1][0] + s[1][1] + s[1][2] + s[1][3];
        float p = s[2][0] + s[2][1] + s[2][2] + s[2][3];
        atomicAdd(out + 0, r * (1.f / 16.f));
        atomicAdd(out + 1, c * (1.f / 16.f));
        atomicAdd(out + 2, p * (1.f / 16.f));
    }
}

extern "C" void kernel_launch(void* const* d_in, const int* in_sizes, int n_in,
                              void* d_out, int out_size, void* d_ws, size_t ws_size,
                              hipStream_t stream) {
    const float* f0 = (const float*)d_in[0];
    const float* f1 = (const float*)d_in[1];
    const float* f2 = (const float*)d_in[2];
    const float* l0 = (const float*)d_in[3];
    const float* l1 = (const float*)d_in[4];
    const float* l2 = (const float*)d_in[5];
    float* out = (float*)d_out;

    int* counts = (int*)d_ws;                       // 48 ints (3 levels x 16 imgs)
    float4* boxes = (float4*)((char*)d_ws + 256);   // 48 * 64 boxes

    hipMemsetAsync(d_out, 0, 3 * sizeof(float), stream);
    hipMemsetAsync(d_ws, 0, 256, stream);

    const int threads = 256;
    const int blocks = (CTOT + threads - 1) / threads;  // 666
    collect_pos<<<blocks, threads, 0, stream>>>(l0, l1, l2, counts, boxes);
    yolo_loss<<<blocks, threads, 0, stream>>>(f0, f1, f2, l0, l1, l2,
                                              counts, boxes, out);
}

// Round 2
// 216.770 us; speedup vs baseline: 1.0026x; 1.0026x over previous
//
#include <hip/hip_runtime.h>

// YOLO loss, 3 levels. Inputs (fp32):
//   d_in[0..2] = pred0/1/2  (N=16, C=255, H, W), H=W in {52,26,13}
//   d_in[3..5] = label0/1/2 (N, H, W, 3, 85)
// Output: d_out = [reg, conf, prob] fp32.
//
// R2 design: the only per-cell label info needed is conf (0/1, ~0.08% ones).
//  A) scan_labels: stream all 58 MB of labels with coalesced float4 loads;
//     elements with index ≡ 4 (mod 85) are confs. Compact positive cells
//     (box + cell index) into workspace. ~12 us BW-bound vs ~100 us for the
//     scattered per-record read (R1's 130 GB/s latency-bound pathology).
//  B) yolo_loss: ZERO label reads on the negative path. A thread learns it
//     is positive by matching its cell id against the compacted list inside
//     the IoU loop it already runs. Positive threads (~136 total) read their
//     85-float label record + 80 prob channels (negligible).

#define LVLS 3
#define NIMG 16
#define MAXB 64

// per-level cell counts (cell = (n,h,w,a)): N*3*H*W
#define C0 (16 * 3 * 52 * 52)   // 129792
#define C1 (16 * 3 * 26 * 26)   // 32448
#define C2 (16 * 3 * 13 * 13)   // 8112
#define CTOT (C0 + C1 + C2)     // 170352

// label float counts per level (N*H*W*3*85) and float4 counts
#define E0 (C0 * 85)            // 11,032,320
#define E1 (C1 * 85)            //  2,758,080
#define E2 (C2 * 85)            //    689,520
#define T0 (E0 / 4)             //  2,758,080 float4s
#define T1 (E1 / 4)
#define T2 (E2 / 4)
#define TTOT (T0 + T1 + T2)     //  3,619,980

__device__ __constant__ float d_anchors[3][3][2] = {
    {{12.f, 16.f}, {19.f, 36.f}, {40.f, 28.f}},
    {{36.f, 75.f}, {76.f, 55.f}, {72.f, 146.f}},
    {{142.f, 110.f}, {192.f, 243.f}, {459.f, 401.f}}};

__device__ __forceinline__ float bce_logits(float x, float t) {
    return fmaxf(x, 0.f) - x * t + log1pf(expf(-fabsf(x)));
}

// ---------------- Kernel A: streaming positive-box compaction ----------------
// Grid-stride over all label float4s of all 3 levels. Element index e within
// a level is a conf iff e % 85 == 4. A float4 at element base eb=4*i contains
// one conf iff r = eb%85 is in {1,2,3,4} (the conf sits at lane j = 4-r).
__global__ void scan_labels(const float* __restrict__ l0,
                            const float* __restrict__ l1,
                            const float* __restrict__ l2,
                            int* __restrict__ counts,
                            float4* __restrict__ boxes,
                            int* __restrict__ cellids) {
    int stride = gridDim.x * blockDim.x;
    for (int gi = blockIdx.x * blockDim.x + threadIdx.x; gi < TTOT; gi += stride) {
        const float* lab;
        int level, i, hw3;
        if (gi < T0)           { level = 0; i = gi;           lab = l0; hw3 = 3 * 52 * 52; }
        else if (gi < T0 + T1) { level = 1; i = gi - T0;      lab = l1; hw3 = 3 * 26 * 26; }
        else                   { level = 2; i = gi - T0 - T1; lab = l2; hw3 = 3 * 13 * 13; }

        float4 v = ((const float4*)lab)[i];
        unsigned eb = 4u * (unsigned)i;
        unsigned r = eb % 85u;                  // magic-mul, cheap
        if (r >= 1u && r <= 4u) {
            int j = 4 - (int)r;
            float c = (j == 0) ? v.x : (j == 1) ? v.y : (j == 2) ? v.z : v.w;
            if (c > 0.f) {                      // positive cell (rare: ~0.08%)
                unsigned e = eb + (unsigned)j;  // e % 85 == 4
                int cell = (int)(e / 85u);      // (n*HW + hw)*3 + a
                int n = cell / hw3;
                int p = atomicAdd(&counts[level * NIMG + n], 1);
                if (p < MAXB) {
                    const float* lp = lab + (size_t)cell * 85;
                    float4 b;
                    b.x = lp[0]; b.y = lp[1]; b.z = lp[2]; b.w = lp[3];
                    boxes[(level * NIMG + n) * MAXB + p] = b;
                    cellids[(level * NIMG + n) * MAXB + p] = cell;
                }
            }
        }
    }
}

// ---------------- Kernel B: fused loss, no negative-path label reads --------
// cell enumeration (feature-friendly): cell_f = ((n*3+a)*H + h)*W + w
// feature element (n, a*85+j, h, w) = f[n*255*HW + (a*85+j)*HW + hw]
// label-order cell id for membership check: cell_lab = (n*HW + hw)*3 + a
__global__ void yolo_loss(const float* __restrict__ f0,
                          const float* __restrict__ f1,
                          const float* __restrict__ f2,
                          const float* __restrict__ l0,
                          const float* __restrict__ l1,
                          const float* __restrict__ l2,
                          const int* __restrict__ counts,
                          const float4* __restrict__ boxes,
                          const int* __restrict__ cellids,
                          float* __restrict__ out) {
    int gid = blockIdx.x * blockDim.x + threadIdx.x;

    float reg = 0.f, conf = 0.f, prob = 0.f;

    if (gid < CTOT) {
        const float *f, *lab;
        int level, cell, W, HW;
        float stride;
        if (gid < C0)           { level = 0; cell = gid;           f = f0; lab = l0; W = 52; HW = 52 * 52; stride = 8.f; }
        else if (gid < C0 + C1) { level = 1; cell = gid - C0;      f = f1; lab = l1; W = 26; HW = 26 * 26; stride = 16.f; }
        else                    { level = 2; cell = gid - C0 - C1; f = f2; lab = l2; W = 13; HW = 13 * 13; stride = 32.f; }

        int hw = cell % HW;
        int na = cell / HW;
        int a = na % 3;
        int n = na / 3;
        int w = hw % W;
        int h = hw / W;
        int cell_lab = (n * HW + hw) * 3 + a;

        const float* fp = f + (size_t)n * 255 * HW + (size_t)a * 85 * HW + hw;

        float rx = fp[0];
        float ry = fp[HW];
        float rw = fp[2 * HW];
        float rh = fp[3 * HW];
        float rc = fp[4 * HW];

        float aw = d_anchors[level][a][0];
        float ah = d_anchors[level][a][1];

        // pred box (pixel coords)
        float px = (1.f / (1.f + expf(-rx)) + (float)w) * stride;
        float py = (1.f / (1.f + expf(-ry)) + (float)h) * stride;
        float pw = expf(rw) * aw;
        float ph = expf(rh) * ah;

        // IoU loop over this image's positive boxes; also membership check
        int m = counts[level * NIMG + n];
        if (m > MAXB) m = MAXB;
        int base = (level * NIMG + n) * MAXB;
        float parea = pw * ph;
        float pl = px - pw * 0.5f, pr = px + pw * 0.5f;
        float pt = py - ph * 0.5f, pb = py + ph * 0.5f;
        float maxiou = 0.f;
        bool ispos = false;
        for (int i = 0; i < m; ++i) {
            float4 b = boxes[base + i];
            if (cellids[base + i] == cell_lab) ispos = true;
            float tl = b.x - b.z * 0.5f, tr = b.x + b.z * 0.5f;
            float tt = b.y - b.w * 0.5f, tb = b.y + b.w * 0.5f;
            float iw = fminf(pr, tr) - fmaxf(pl, tl);
            float ih = fminf(pb, tb) - fmaxf(pt, tt);
            iw = fmaxf(iw, 0.f);
            ih = fmaxf(ih, 0.f);
            float inter = iw * ih;
            float uni = parea + b.z * b.w - inter;
            float iou = inter / fmaxf(uni, 1e-9f);
            maxiou = fmaxf(maxiou, iou);
        }

        // conf loss: positive -> bce(rc,1); negative -> ignore_mask*bce(rc,0)
        if (ispos) {
            conf = bce_logits(rc, 1.f);
        } else {
            conf = (maxiou < 0.5f) ? bce_logits(rc, 0.f) : 0.f;
        }

        if (ispos) {   // ~136 threads total take this branch
            const float* lp = lab + (size_t)cell_lab * 85;
            float lx = lp[0], ly = lp[1], lw = lp[2], lh = lp[3];
            float ox = lx / stride - (float)w;
            float oy = ly / stride - (float)h;
            float ow = logf(lw / aw + 1e-7f);
            float oh = logf(lh / ah + 1e-7f);
            float scale = 2.f - lw * lh * (1.f / (416.f * 416.f));
            float xyl = scale * (bce_logits(rx, ox) + bce_logits(ry, oy));
            float dw = rw - ow, dh = rh - oh;
            float whl = scale * 0.5f * (dw * dw + dh * dh);
            reg = xyl + whl;

            float p = 0.f;
            #pragma unroll 4
            for (int j = 0; j < 80; ++j)
                p += bce_logits(fp[(5 + j) * HW], lp[5 + j]);
            prob = p;
        }
    }

    // wave (64) reduce, then block reduce across 4 waves, then atomics
    for (int off = 32; off > 0; off >>= 1) {
        reg += __shfl_down(reg, off);
        conf += __shfl_down(conf, off);
        prob += __shfl_down(prob, off);
    }
    __shared__ float s[3][4];
    int lane = threadIdx.x & 63;
    int wid = threadIdx.x >> 6;
    if (lane == 0) { s[0][wid] = reg; s[1][wid] = conf; s[2][wid] = prob; }
    __syncthreads();
    if (threadIdx.x == 0) {
        float r = s[0][0] + s[0][1] + s[0][2] + s[0][3];
        float c = s[1][0] + s[1][1] + s[1][2] + s[1][3];
        float p = s[2][0] + s[2][1] + s[2][2] + s[2][3];
        atomicAdd(out + 0, r * (1.f / 16.f));
        atomicAdd(out + 1, c * (1.f / 16.f));
        atomicAdd(out + 2, p * (1.f / 16.f));
    }
}

extern "C" void kernel_launch(void* const* d_in, const int* in_sizes, int n_in,
                              void* d_out, int out_size, void* d_ws, size_t ws_size,
                              hipStream_t stream) {
    const float* f0 = (const float*)d_in[0];
    const float* f1 = (const float*)d_in[1];
    const float* f2 = (const float*)d_in[2];
    const float* l0 = (const float*)d_in[3];
    const float* l1 = (const float*)d_in[4];
    const float* l2 = (const float*)d_in[5];
    float* out = (float*)d_out;

    int* counts = (int*)d_ws;                             // 48 ints, pad to 256 B
    float4* boxes = (float4*)((char*)d_ws + 256);         // 48*64*16 B = 49152
    int* cellids = (int*)((char*)d_ws + 256 + 49152);     // 48*64*4 B = 12288

    hipMemsetAsync(d_out, 0, 3 * sizeof(float), stream);
    hipMemsetAsync(d_ws, 0, 256, stream);

    // A: streaming scan, BW-bound over 58 MB of labels
    scan_labels<<<2048, 256, 0, stream>>>(l0, l1, l2, counts, boxes, cellids);

    // B: fused loss
    const int threads = 256;
    const int blocks = (CTOT + threads - 1) / threads;    // 666
    yolo_loss<<<blocks, threads, 0, stream>>>(f0, f1, f2, l0, l1, l2,
                                              counts, boxes, cellids, out);
}

// Round 3
// 207.688 us; speedup vs baseline: 1.0465x; 1.0437x over previous
//
#include <hip/hip_runtime.h>

// YOLO loss, 3 levels. Inputs (fp32):
//   d_in[0..2] = pred0/1/2  (N=16, C=255, H, W), H=W in {52,26,13}
//   d_in[3..5] = label0/1/2 (N, H, W, 3, 85)
// Output: d_out = [reg, conf, prob] fp32.
//
// R3: R2's yolo_loss was 93 us with only 2.7 MB fetched and VALU 5% -> the
// 666 blocks x 3 atomicAdd to the SAME cacheline serialized (~112 cyc each
// x 1998 = 223K cyc = the whole kernel). Replace with per-block partial
// stores (distinct addresses, fully parallel) + 1-block finalize kernel
// that writes out[] directly (no d_out memset, no atomics anywhere hot).

#define LVLS 3
#define NIMG 16
#define MAXB 64

// per-level cell counts: N*3*H*W
#define C0 (16 * 3 * 52 * 52)   // 129792
#define C1 (16 * 3 * 26 * 26)   // 32448
#define C2 (16 * 3 * 13 * 13)   // 8112
#define CTOT (C0 + C1 + C2)     // 170352
#define NBLK ((CTOT + 255) / 256)  // 666

// label float4 counts per level (N*H*W*3*85/4)
#define T0 (C0 * 85 / 4)        // 2,758,080
#define T1 (C1 * 85 / 4)        //   689,520
#define T2 (C2 * 85 / 4)        //   172,380
#define TTOT (T0 + T1 + T2)     // 3,619,980

// workspace layout (bytes)
#define WS_COUNTS   0           // 48 ints (memset to 0)
#define WS_BOXES    256         // 48*64 float4 = 49152 B
#define WS_CELLIDS  49408       // 48*64 int    = 12288 B
#define WS_PARTIAL  65536       // float[3][1024] = 12288 B

__device__ __constant__ float d_anchors[3][3][2] = {
    {{12.f, 16.f}, {19.f, 36.f}, {40.f, 28.f}},
    {{36.f, 75.f}, {76.f, 55.f}, {72.f, 146.f}},
    {{142.f, 110.f}, {192.f, 243.f}, {459.f, 401.f}}};

__device__ __forceinline__ float bce_logits(float x, float t) {
    return fmaxf(x, 0.f) - x * t + log1pf(expf(-fabsf(x)));
}

// ---------------- Kernel A: streaming positive-box compaction ----------------
// Elements with index % 85 == 4 are confs. A float4 at element base eb=4*i
// holds a conf iff r = eb%85 in {1..4} (conf at lane j = 4-r). Positives are
// ~0.08% so the atomicAdd here is rare (48 distinct counters, ~136 total).
__global__ void scan_labels(const float* __restrict__ l0,
                            const float* __restrict__ l1,
                            const float* __restrict__ l2,
                            int* __restrict__ counts,
                            float4* __restrict__ boxes,
                            int* __restrict__ cellids) {
    int stride = gridDim.x * blockDim.x;
    for (int gi = blockIdx.x * blockDim.x + threadIdx.x; gi < TTOT; gi += stride) {
        const float* lab;
        int level, i, hw3;
        if (gi < T0)           { level = 0; i = gi;           lab = l0; hw3 = 3 * 52 * 52; }
        else if (gi < T0 + T1) { level = 1; i = gi - T0;      lab = l1; hw3 = 3 * 26 * 26; }
        else                   { level = 2; i = gi - T0 - T1; lab = l2; hw3 = 3 * 13 * 13; }

        float4 v = ((const float4*)lab)[i];
        unsigned eb = 4u * (unsigned)i;
        unsigned r = eb % 85u;                  // const modulus -> magic mul
        if (r >= 1u && r <= 4u) {
            int j = 4 - (int)r;
            float c = (j == 0) ? v.x : (j == 1) ? v.y : (j == 2) ? v.z : v.w;
            if (c > 0.f) {
                unsigned e = eb + (unsigned)j;  // e % 85 == 4
                int cell = (int)(e / 85u);      // (n*HW + hw)*3 + a
                int n = cell / hw3;
                int p = atomicAdd(&counts[level * NIMG + n], 1);
                if (p < MAXB) {
                    const float* lp = lab + (size_t)cell * 85;
                    float4 b;
                    b.x = lp[0]; b.y = lp[1]; b.z = lp[2]; b.w = lp[3];
                    boxes[(level * NIMG + n) * MAXB + p] = b;
                    cellids[(level * NIMG + n) * MAXB + p] = cell;
                }
            }
        }
    }
}

// ---------------- Kernel B: fused loss, per-block partials ----------------
// cell enumeration (feature-friendly): cell = ((n*3+a)*H + h)*W + w
// feature element (n, a*85+j, h, w) = f[n*255*HW + (a*85+j)*HW + hw]
// label-order cell id (for positive membership): (n*HW + hw)*3 + a
__global__ void yolo_loss(const float* __restrict__ f0,
                          const float* __restrict__ f1,
                          const float* __restrict__ f2,
                          const float* __restrict__ l0,
                          const float* __restrict__ l1,
                          const float* __restrict__ l2,
                          const int* __restrict__ counts,
                          const float4* __restrict__ boxes,
                          const int* __restrict__ cellids,
                          float* __restrict__ partial) {  // [3][1024]
    int gid = blockIdx.x * blockDim.x + threadIdx.x;

    float reg = 0.f, conf = 0.f, prob = 0.f;

    if (gid < CTOT) {
        const float *f, *lab;
        int level, cell, W, HW;
        float stride;
        if (gid < C0)           { level = 0; cell = gid;           f = f0; lab = l0; W = 52; HW = 52 * 52; stride = 8.f; }
        else if (gid < C0 + C1) { level = 1; cell = gid - C0;      f = f1; lab = l1; W = 26; HW = 26 * 26; stride = 16.f; }
        else                    { level = 2; cell = gid - C0 - C1; f = f2; lab = l2; W = 13; HW = 13 * 13; stride = 32.f; }

        int hw = cell % HW;
        int na = cell / HW;
        int a = na % 3;
        int n = na / 3;
        int w = hw % W;
        int h = hw / W;
        int cell_lab = (n * HW + hw) * 3 + a;

        const float* fp = f + (size_t)n * 255 * HW + (size_t)a * 85 * HW + hw;

        float rx = fp[0];
        float ry = fp[HW];
        float rw = fp[2 * HW];
        float rh = fp[3 * HW];
        float rc = fp[4 * HW];

        float aw = d_anchors[level][a][0];
        float ah = d_anchors[level][a][1];

        float px = (1.f / (1.f + expf(-rx)) + (float)w) * stride;
        float py = (1.f / (1.f + expf(-ry)) + (float)h) * stride;
        float pw = expf(rw) * aw;
        float ph = expf(rh) * ah;

        int m = counts[level * NIMG + n];
        if (m > MAXB) m = MAXB;
        int base = (level * NIMG + n) * MAXB;
        float parea = pw * ph;
        float pl = px - pw * 0.5f, pr = px + pw * 0.5f;
        float pt = py - ph * 0.5f, pb = py + ph * 0.5f;
        float maxiou = 0.f;
        bool ispos = false;
        for (int i = 0; i < m; ++i) {
            float4 b = boxes[base + i];
            if (cellids[base + i] == cell_lab) ispos = true;
            float tl = b.x - b.z * 0.5f, tr = b.x + b.z * 0.5f;
            float tt = b.y - b.w * 0.5f, tb = b.y + b.w * 0.5f;
            float iw = fminf(pr, tr) - fmaxf(pl, tl);
            float ih = fminf(pb, tb) - fmaxf(pt, tt);
            iw = fmaxf(iw, 0.f);
            ih = fmaxf(ih, 0.f);
            float inter = iw * ih;
            float uni = parea + b.z * b.w - inter;
            float iou = inter / fmaxf(uni, 1e-9f);
            maxiou = fmaxf(maxiou, iou);
        }

        if (ispos) {
            conf = bce_logits(rc, 1.f);
        } else {
            conf = (maxiou < 0.5f) ? bce_logits(rc, 0.f) : 0.f;
        }

        if (ispos) {   // ~136 threads total across the grid
            const float* lp = lab + (size_t)cell_lab * 85;
            float lx = lp[0], ly = lp[1], lw = lp[2], lh = lp[3];
            float ox = lx / stride - (float)w;
            float oy = ly / stride - (float)h;
            float ow = logf(lw / aw + 1e-7f);
            float oh = logf(lh / ah + 1e-7f);
            float scale = 2.f - lw * lh * (1.f / (416.f * 416.f));
            float xyl = scale * (bce_logits(rx, ox) + bce_logits(ry, oy));
            float dw = rw - ow, dh = rh - oh;
            float whl = scale * 0.5f * (dw * dw + dh * dh);
            reg = xyl + whl;

            float p = 0.f;
            #pragma unroll 4
            for (int j = 0; j < 80; ++j)
                p += bce_logits(fp[(5 + j) * HW], lp[5 + j]);
            prob = p;
        }
    }

    // wave(64) shuffle reduce -> 4-wave LDS reduce -> one partial store/block
    for (int off = 32; off > 0; off >>= 1) {
        reg += __shfl_down(reg, off);
        conf += __shfl_down(conf, off);
        prob += __shfl_down(prob, off);
    }
    __shared__ float s[3][4];
    int lane = threadIdx.x & 63;
    int wid = threadIdx.x >> 6;
    if (lane == 0) { s[0][wid] = reg; s[1][wid] = conf; s[2][wid] = prob; }
    __syncthreads();
    if (threadIdx.x == 0) {
        partial[0 * 1024 + blockIdx.x] = s[0][0] + s[0][1] + s[0][2] + s[0][3];
        partial[1 * 1024 + blockIdx.x] = s[1][0] + s[1][1] + s[1][2] + s[1][3];
        partial[2 * 1024 + blockIdx.x] = s[2][0] + s[2][1] + s[2][2] + s[2][3];
    }
}

// ---------------- Kernel C: finalize (1 block) ----------------
__global__ void finalize(const float* __restrict__ partial,  // [3][1024]
                         float* __restrict__ out) {
    float acc[3] = {0.f, 0.f, 0.f};
    for (int c = 0; c < 3; ++c)
        for (int i = threadIdx.x; i < NBLK; i += 256)
            acc[c] += partial[c * 1024 + i];
    for (int off = 32; off > 0; off >>= 1) {
        acc[0] += __shfl_down(acc[0], off);
        acc[1] += __shfl_down(acc[1], off);
        acc[2] += __shfl_down(acc[2], off);
    }
    __shared__ float s[3][4];
    int lane = threadIdx.x & 63;
    int wid = threadIdx.x >> 6;
    if (lane == 0) { s[0][wid] = acc[0]; s[1][wid] = acc[1]; s[2][wid] = acc[2]; }
    __syncthreads();
    if (threadIdx.x == 0) {
        out[0] = (s[0][0] + s[0][1] + s[0][2] + s[0][3]) * (1.f / 16.f);
        out[1] = (s[1][0] + s[1][1] + s[1][2] + s[1][3]) * (1.f / 16.f);
        out[2] = (s[2][0] + s[2][1] + s[2][2] + s[2][3]) * (1.f / 16.f);
    }
}

extern "C" void kernel_launch(void* const* d_in, const int* in_sizes, int n_in,
                              void* d_out, int out_size, void* d_ws, size_t ws_size,
                              hipStream_t stream) {
    const float* f0 = (const float*)d_in[0];
    const float* f1 = (const float*)d_in[1];
    const float* f2 = (const float*)d_in[2];
    const float* l0 = (const float*)d_in[3];
    const float* l1 = (const float*)d_in[4];
    const float* l2 = (const float*)d_in[5];
    float* out = (float*)d_out;

    int*    counts  = (int*)((char*)d_ws + WS_COUNTS);
    float4* boxes   = (float4*)((char*)d_ws + WS_BOXES);
    int*    cellids = (int*)((char*)d_ws + WS_CELLIDS);
    float*  partial = (float*)((char*)d_ws + WS_PARTIAL);

    hipMemsetAsync(d_ws, 0, 256, stream);   // counts only

    scan_labels<<<2048, 256, 0, stream>>>(l0, l1, l2, counts, boxes, cellids);
    yolo_loss<<<NBLK, 256, 0, stream>>>(f0, f1, f2, l0, l1, l2,
                                        counts, boxes, cellids, partial);
    finalize<<<1, 256, 0, stream>>>(partial, out);
}

// Round 5
// 143.546 us; speedup vs baseline: 1.5141x; 1.4468x over previous
//
#include <hip/hip_runtime.h>

// YOLO loss, 3 levels. Inputs (fp32):
//   d_in[0..2] = pred (N=16, C=255, H, W), d_in[3..5] = label (N, H, W, 3, 85)
// Output: d_out = [reg, conf, prob] fp32.
//
// R5: coop launch (R4) silently failed -> back to stream-ordered kernels.
// R3 evidence: conf kernel 85us @ 2.7MB, occupancy 5% = tail of ~136 positive
// threads doing ~160 SERIALIZED scattered loads each. Fix: dedicated pos_loss
// kernel, ONE WAVE per positive box, prob channels spread across lanes ->
// 2 wave-wide gathers (64 misses in flight). Conf kernel has no positive
// branch at all. scan_labels batches 4 float4 loads in flight.
// Pipeline: memset(counts) -> scan -> conf -> pos -> finalize.

#define NIMG 16
#define MAXB 64

// per-level cell counts: N*3*H*W
#define C0 (16 * 3 * 52 * 52)   // 129792
#define C1 (16 * 3 * 26 * 26)   // 32448
#define C2 (16 * 3 * 13 * 13)   // 8112
#define CTOT (C0 + C1 + C2)     // 170352
#define NBLK ((CTOT + 255) / 256)  // 666 conf blocks

// label float4 counts per level; E0 = C0*85 and E0+E1 are multiples of 85,
// so global float4 index math (4*gi) % 85 / div 85 works across levels.
#define T0 (C0 * 85 / 4)        // 2,758,080
#define T1 (C1 * 85 / 4)        //   689,520
#define T2 (C2 * 85 / 4)        //   172,380
#define TTOT (T0 + T1 + T2)     // 3,619,980

#define SCAN_BLOCKS 1024
#define SCAN_BATCH 4
#define SCAN_NT (SCAN_BLOCKS * 256)

// workspace layout (bytes)
#define WS_COUNTS   0           // 48 ints (memset to 0)
#define WS_BOXES    256         // 48*64 float4 = 49152
#define WS_CELLIDS  49408       // 48*64 int    = 12288
#define WS_PARTIAL  65536       // float[3][1024]: [0]=reg(48), [1]=conf(666), [2]=prob(48)

__device__ __constant__ float d_anchors[3][3][2] = {
    {{12.f, 16.f}, {19.f, 36.f}, {40.f, 28.f}},
    {{36.f, 75.f}, {76.f, 55.f}, {72.f, 146.f}},
    {{142.f, 110.f}, {192.f, 243.f}, {459.f, 401.f}}};

__device__ __forceinline__ float bce_logits(float x, float t) {
    return fmaxf(x, 0.f) - x * t + log1pf(expf(-fabsf(x)));
}

// ---------------- Kernel A: scan labels, compact positive boxes ----------------
// float4 gi holds a conf iff r = (4*gi)%85 in {1..4}; conf at lane j = 4-r.
__global__ void scan_labels(const float* __restrict__ l0,
                            const float* __restrict__ l1,
                            const float* __restrict__ l2,
                            int* __restrict__ counts,
                            float4* __restrict__ boxes,
                            int* __restrict__ cellids) {
    int tid = blockIdx.x * blockDim.x + threadIdx.x;
    for (int base = tid; base < TTOT; base += SCAN_BATCH * SCAN_NT) {
        float4 v[SCAN_BATCH];
        #pragma unroll
        for (int k = 0; k < SCAN_BATCH; ++k) {     // issue all loads first
            int gi = base + k * SCAN_NT;
            if (gi < TTOT) {
                const float* p; int i;
                if (gi < T0)           { p = l0; i = gi; }
                else if (gi < T0 + T1) { p = l1; i = gi - T0; }
                else                   { p = l2; i = gi - T0 - T1; }
                v[k] = ((const float4*)p)[i];
            }
        }
        #pragma unroll
        for (int k = 0; k < SCAN_BATCH; ++k) {
            int gi = base + k * SCAN_NT;
            if (gi >= TTOT) continue;
            unsigned r = (4u * (unsigned)gi) % 85u;   // const mod -> magic mul
            if (r < 1u || r > 4u) continue;
            int j = 4 - (int)r;
            float c = (j == 0) ? v[k].x : (j == 1) ? v[k].y : (j == 2) ? v[k].z : v[k].w;
            if (c <= 0.f) continue;                   // ~0.08% pass
            unsigned recg = (4u * (unsigned)gi + (unsigned)j) / 85u;  // global record
            int level, cell, hw3; const float* lab;
            if ((int)recg < C0)           { level = 0; cell = (int)recg;           lab = l0; hw3 = 3 * 52 * 52; }
            else if ((int)recg < C0 + C1) { level = 1; cell = (int)recg - C0;      lab = l1; hw3 = 3 * 26 * 26; }
            else                          { level = 2; cell = (int)recg - C0 - C1; lab = l2; hw3 = 3 * 13 * 13; }
            int n = cell / hw3;
            int p = atomicAdd(&counts[level * NIMG + n], 1);
            if (p < MAXB) {
                const float* lp = lab + (size_t)cell * 85;
                float4 b;
                b.x = lp[0]; b.y = lp[1]; b.z = lp[2]; b.w = lp[3];
                boxes[(level * NIMG + n) * MAXB + p] = b;
                cellids[(level * NIMG + n) * MAXB + p] = cell;
            }
        }
    }
}

// ---------------- Kernel B: conf loss (no positive branch, no label reads) ----
__global__ void conf_loss(const float* __restrict__ f0,
                          const float* __restrict__ f1,
                          const float* __restrict__ f2,
                          const int* __restrict__ counts,
                          const float4* __restrict__ boxes,
                          const int* __restrict__ cellids,
                          float* __restrict__ partial) {
    int gid = blockIdx.x * blockDim.x + threadIdx.x;
    float conf = 0.f;

    if (gid < CTOT) {
        const float* f;
        int level, cell, W, HW;
        float stride;
        if (gid < C0)           { level = 0; cell = gid;           f = f0; W = 52; HW = 52 * 52; stride = 8.f; }
        else if (gid < C0 + C1) { level = 1; cell = gid - C0;      f = f1; W = 26; HW = 26 * 26; stride = 16.f; }
        else                    { level = 2; cell = gid - C0 - C1; f = f2; W = 13; HW = 13 * 13; stride = 32.f; }

        int hw = cell % HW;
        int na = cell / HW;
        int a = na % 3;
        int n = na / 3;
        int w = hw % W;
        int h = hw / W;
        int cell_lab = (n * HW + hw) * 3 + a;

        const float* fp = f + (size_t)n * 255 * HW + (size_t)a * 85 * HW + hw;
        float rx = fp[0];
        float ry = fp[HW];
        float rw = fp[2 * HW];
        float rh = fp[3 * HW];
        float rc = fp[4 * HW];

        float aw = d_anchors[level][a][0];
        float ah = d_anchors[level][a][1];
        float px = (1.f / (1.f + expf(-rx)) + (float)w) * stride;
        float py = (1.f / (1.f + expf(-ry)) + (float)h) * stride;
        float pw = expf(rw) * aw;
        float ph = expf(rh) * ah;

        int m = counts[level * NIMG + n];
        if (m > MAXB) m = MAXB;
        int base = (level * NIMG + n) * MAXB;
        float parea = pw * ph;
        float pl = px - pw * 0.5f, pr = px + pw * 0.5f;
        float pt = py - ph * 0.5f, pb = py + ph * 0.5f;
        float maxiou = 0.f;
        bool ispos = false;
        for (int i = 0; i < m; ++i) {
            float4 b = boxes[base + i];
            if (cellids[base + i] == cell_lab) ispos = true;
            float tl = b.x - b.z * 0.5f, tr = b.x + b.z * 0.5f;
            float tt = b.y - b.w * 0.5f, tb = b.y + b.w * 0.5f;
            float iw = fmaxf(fminf(pr, tr) - fmaxf(pl, tl), 0.f);
            float ih = fmaxf(fminf(pb, tb) - fmaxf(pt, tt), 0.f);
            float inter = iw * ih;
            float uni = parea + b.z * b.w - inter;
            float iou = inter / fmaxf(uni, 1e-9f);
            maxiou = fmaxf(maxiou, iou);
        }
        if (ispos)              conf = bce_logits(rc, 1.f);
        else if (maxiou < 0.5f) conf = bce_logits(rc, 0.f);
    }

    for (int off = 32; off > 0; off >>= 1) conf += __shfl_down(conf, off);
    __shared__ float s[4];
    int lane = threadIdx.x & 63;
    int wid = threadIdx.x >> 6;
    if (lane == 0) s[wid] = conf;
    __syncthreads();
    if (threadIdx.x == 0)
        partial[1 * 1024 + blockIdx.x] = s[0] + s[1] + s[2] + s[3];
}

// ---------------- Kernel C: positives, one wave per box ----------------
// 48 blocks = (level, image). Lanes 0..39 each handle prob channels
// (5+lane) and (45+lane); lanes 40..43 carry raw xy/wh in the same gather.
__global__ void pos_loss(const float* __restrict__ f0,
                         const float* __restrict__ f1,
                         const float* __restrict__ f2,
                         const float* __restrict__ l0,
                         const float* __restrict__ l1,
                         const float* __restrict__ l2,
                         const int* __restrict__ counts,
                         const float4* __restrict__ boxes,
                         const int* __restrict__ cellids,
                         float* __restrict__ partial) {
    int level = blockIdx.x / NIMG;
    int n = blockIdx.x % NIMG;
    const float *f, *lab;
    int W, HW; float stride;
    if (level == 0)      { f = f0; lab = l0; W = 52; HW = 52 * 52; stride = 8.f; }
    else if (level == 1) { f = f1; lab = l1; W = 26; HW = 26 * 26; stride = 16.f; }
    else                 { f = f2; lab = l2; W = 13; HW = 13 * 13; stride = 32.f; }

    int m = counts[blockIdx.x];
    if (m > MAXB) m = MAXB;
    int bbase = blockIdx.x * MAXB;

    int lane = threadIdx.x & 63;
    int wid = threadIdx.x >> 6;
    float reg_acc = 0.f, prob_acc = 0.f;

    for (int i = wid; i < m; i += 4) {           // one wave per positive box
        int cell = cellids[bbase + i];           // (n*HW + hw)*3 + a
        float4 b = boxes[bbase + i];
        int a = cell % 3;
        int hw = (cell / 3) % HW;
        int w = hw % W;
        int h = hw / W;
        const float* fp = f + ((size_t)n * 255 + (size_t)a * 85) * HW + hw;
        const float* lp = lab + (size_t)cell * 85;

        int ch1 = (lane < 40) ? (5 + lane) : ((lane < 44) ? (lane - 40) : 0);
        float g1 = fp[(size_t)ch1 * HW];                           // wave gather 1
        float g2 = fp[(size_t)((lane < 40) ? (45 + lane) : 0) * HW]; // wave gather 2
        float t1 = lp[(lane < 40) ? (5 + lane) : 0];
        float t2 = lp[(lane < 40) ? (45 + lane) : 0];

        float pp = (lane < 40) ? (bce_logits(g1, t1) + bce_logits(g2, t2)) : 0.f;
        for (int off = 32; off > 0; off >>= 1) pp += __shfl_down(pp, off);

        float rx = __shfl(g1, 40);
        float ry = __shfl(g1, 41);
        float rw = __shfl(g1, 42);
        float rh = __shfl(g1, 43);
        if (lane == 0) {
            prob_acc += pp;
            float aw = d_anchors[level][a][0];
            float ah = d_anchors[level][a][1];
            float ox = b.x / stride - (float)w;
            float oy = b.y / stride - (float)h;
            float ow = logf(b.z / aw + 1e-7f);
            float oh = logf(b.w / ah + 1e-7f);
            float scale = 2.f - b.z * b.w * (1.f / (416.f * 416.f));
            float dw = rw - ow, dh = rh - oh;
            reg_acc += scale * (bce_logits(rx, ox) + bce_logits(ry, oy))
                     + scale * 0.5f * (dw * dw + dh * dh);
        }
    }

    __shared__ float s[2][4];
    if (lane == 0) { s[0][wid] = reg_acc; s[1][wid] = prob_acc; }
    __syncthreads();
    if (threadIdx.x == 0) {
        partial[0 * 1024 + blockIdx.x] = s[0][0] + s[0][1] + s[0][2] + s[0][3];
        partial[2 * 1024 + blockIdx.x] = s[1][0] + s[1][1] + s[1][2] + s[1][3];
    }
}

// ---------------- Kernel D: finalize (1 block) ----------------
__global__ void finalize(const float* __restrict__ partial,
                         float* __restrict__ out) {
    float a0 = 0.f, a1 = 0.f, a2 = 0.f;
    for (int i = threadIdx.x; i < NBLK; i += 256) {
        a1 += partial[1 * 1024 + i];
        if (i < 48) {
            a0 += partial[0 * 1024 + i];
            a2 += partial[2 * 1024 + i];
        }
    }
    for (int off = 32; off > 0; off >>= 1) {
        a0 += __shfl_down(a0, off);
        a1 += __shfl_down(a1, off);
        a2 += __shfl_down(a2, off);
    }
    __shared__ float s[3][4];
    int lane = threadIdx.x & 63;
    int wid = threadIdx.x >> 6;
    if (lane == 0) { s[0][wid] = a0; s[1][wid] = a1; s[2][wid] = a2; }
    __syncthreads();
    if (threadIdx.x == 0) {
        out[0] = (s[0][0] + s[0][1] + s[0][2] + s[0][3]) * (1.f / 16.f);
        out[1] = (s[1][0] + s[1][1] + s[1][2] + s[1][3]) * (1.f / 16.f);
        out[2] = (s[2][0] + s[2][1] + s[2][2] + s[2][3]) * (1.f / 16.f);
    }
}

extern "C" void kernel_launch(void* const* d_in, const int* in_sizes, int n_in,
                              void* d_out, int out_size, void* d_ws, size_t ws_size,
                              hipStream_t stream) {
    const float* f0 = (const float*)d_in[0];
    const float* f1 = (const float*)d_in[1];
    const float* f2 = (const float*)d_in[2];
    const float* l0 = (const float*)d_in[3];
    const float* l1 = (const float*)d_in[4];
    const float* l2 = (const float*)d_in[5];
    float* out = (float*)d_out;

    int*    counts  = (int*)((char*)d_ws + WS_COUNTS);
    float4* boxes   = (float4*)((char*)d_ws + WS_BOXES);
    int*    cellids = (int*)((char*)d_ws + WS_CELLIDS);
    float*  partial = (float*)((char*)d_ws + WS_PARTIAL);

    hipMemsetAsync(d_ws, 0, 256, stream);   // zero counts

    scan_labels<<<SCAN_BLOCKS, 256, 0, stream>>>(l0, l1, l2, counts, boxes, cellids);
    conf_loss<<<NBLK, 256, 0, stream>>>(f0, f1, f2, counts, boxes, cellids, partial);
    pos_loss<<<48, 256, 0, stream>>>(f0, f1, f2, l0, l1, l2,
                                     counts, boxes, cellids, partial);
    finalize<<<1, 256, 0, stream>>>(partial, out);
}

// Round 6
// 134.271 us; speedup vs baseline: 1.6187x; 1.0691x over previous
//
#include <hip/hip_runtime.h>

// YOLO loss, 3 levels. Inputs (fp32):
//   d_in[0..2] = pred (N=16, C=255, H, W), d_in[3..5] = label (N, H, W, 3, 85)
// Output: d_out = [reg, conf, prob] fp32.
//
// R6: R5 revealed the harness poison-fill of d_ws (268 MB, 40 us) + input
// restores (~35 us) sit inside the timed window -> floor ~75-80 us. Our
// reducible cost is scan (was streaming 58 MB) + launch gaps.
//  A) scan_labels: conf-ONLY gather — one 4B load per cell (stride 340 B),
//     170K cachelines ~ 11-22 MB fetched vs 58 MB streamed. Rare positives
//     (~136) read their box + get compacted per (level,image).
//  B) loss_fused: blocks [0,NBLK) = conf loss per cell (coalesced channel
//     planes, no label reads, membership via compacted cellids); blocks
//     [NBLK, NBLK+48) = positives, ONE WAVE per box, prob channels spread
//     across lanes (2 wave-wide gathers, 64 misses in flight).
//  C) finalize: 1 block -> out.

#define NIMG 16
#define MAXB 64

// per-level cell counts: N*3*H*W
#define C0 (16 * 3 * 52 * 52)   // 129792
#define C1 (16 * 3 * 26 * 26)   // 32448
#define C2 (16 * 3 * 13 * 13)   // 8112
#define CTOT (C0 + C1 + C2)     // 170352
#define NBLK ((CTOT + 255) / 256)  // 666 conf blocks

// workspace layout (bytes)
#define WS_COUNTS   0           // 48 ints (memset to 0)
#define WS_BOXES    256         // 48*64 float4 = 49152
#define WS_CELLIDS  49408       // 48*64 int    = 12288
#define WS_PARTIAL  65536       // float[3][1024]: [0]=reg(48), [1]=conf(666), [2]=prob(48)

__device__ __constant__ float d_anchors[3][3][2] = {
    {{12.f, 16.f}, {19.f, 36.f}, {40.f, 28.f}},
    {{36.f, 75.f}, {76.f, 55.f}, {72.f, 146.f}},
    {{142.f, 110.f}, {192.f, 243.f}, {459.f, 401.f}}};

__device__ __forceinline__ float bce_logits(float x, float t) {
    return fmaxf(x, 0.f) - x * t + log1pf(expf(-fabsf(x)));
}

// ---------------- Kernel A: conf-only gather + positive compaction ----------
// One thread per cell (label-record order: cell = (n*HW+hw)*3 + a).
// Single scattered 4B load lab[cell*85+4]; positives (~0.08%) read the box.
__global__ void scan_labels(const float* __restrict__ l0,
                            const float* __restrict__ l1,
                            const float* __restrict__ l2,
                            int* __restrict__ counts,
                            float4* __restrict__ boxes,
                            int* __restrict__ cellids) {
    int rec = blockIdx.x * blockDim.x + threadIdx.x;
    if (rec >= CTOT) return;

    const float* lab;
    int level, cell, hw3;
    if (rec < C0)           { level = 0; cell = rec;           lab = l0; hw3 = 3 * 52 * 52; }
    else if (rec < C0 + C1) { level = 1; cell = rec - C0;      lab = l1; hw3 = 3 * 26 * 26; }
    else                    { level = 2; cell = rec - C0 - C1; lab = l2; hw3 = 3 * 13 * 13; }

    const float* lp = lab + (size_t)cell * 85;
    float c = lp[4];                     // the ONLY load for 99.92% of threads
    if (c > 0.f) {
        int n = cell / hw3;
        int p = atomicAdd(&counts[level * NIMG + n], 1);
        if (p < MAXB) {
            float4 b;
            b.x = lp[0]; b.y = lp[1]; b.z = lp[2]; b.w = lp[3];
            boxes[(level * NIMG + n) * MAXB + p] = b;
            cellids[(level * NIMG + n) * MAXB + p] = cell;
        }
    }
}

// ---------------- Kernel B: fused conf (blocks < NBLK) + positives ----------
__global__ void loss_fused(const float* __restrict__ f0,
                           const float* __restrict__ f1,
                           const float* __restrict__ f2,
                           const float* __restrict__ l0,
                           const float* __restrict__ l1,
                           const float* __restrict__ l2,
                           const int* __restrict__ counts,
                           const float4* __restrict__ boxes,
                           const int* __restrict__ cellids,
                           float* __restrict__ partial) {
    int lane = threadIdx.x & 63;
    int wid = threadIdx.x >> 6;

    if (blockIdx.x < NBLK) {
        // ---- conf loss per cell; no label reads, no positive-work branch ----
        int gid = blockIdx.x * blockDim.x + threadIdx.x;
        float conf = 0.f;

        if (gid < CTOT) {
            const float* f;
            int level, cell, W, HW;
            float stride;
            if (gid < C0)           { level = 0; cell = gid;           f = f0; W = 52; HW = 52 * 52; stride = 8.f; }
            else if (gid < C0 + C1) { level = 1; cell = gid - C0;      f = f1; W = 26; HW = 26 * 26; stride = 16.f; }
            else                    { level = 2; cell = gid - C0 - C1; f = f2; W = 13; HW = 13 * 13; stride = 32.f; }

            int hw = cell % HW;
            int na = cell / HW;
            int a = na % 3;
            int n = na / 3;
            int w = hw % W;
            int h = hw / W;
            int cell_lab = (n * HW + hw) * 3 + a;

            const float* fp = f + (size_t)n * 255 * HW + (size_t)a * 85 * HW + hw;
            float rx = fp[0];
            float ry = fp[HW];
            float rw = fp[2 * HW];
            float rh = fp[3 * HW];
            float rc = fp[4 * HW];

            float aw = d_anchors[level][a][0];
            float ah = d_anchors[level][a][1];
            float px = (1.f / (1.f + expf(-rx)) + (float)w) * stride;
            float py = (1.f / (1.f + expf(-ry)) + (float)h) * stride;
            float pw = expf(rw) * aw;
            float ph = expf(rh) * ah;

            int m = counts[level * NIMG + n];
            if (m > MAXB) m = MAXB;
            int base = (level * NIMG + n) * MAXB;
            float parea = pw * ph;
            float pl = px - pw * 0.5f, pr = px + pw * 0.5f;
            float pt = py - ph * 0.5f, pb = py + ph * 0.5f;
            float maxiou = 0.f;
            bool ispos = false;
            for (int i = 0; i < m; ++i) {
                float4 b = boxes[base + i];
                if (cellids[base + i] == cell_lab) ispos = true;
                float tl = b.x - b.z * 0.5f, tr = b.x + b.z * 0.5f;
                float tt = b.y - b.w * 0.5f, tb = b.y + b.w * 0.5f;
                float iw = fmaxf(fminf(pr, tr) - fmaxf(pl, tl), 0.f);
                float ih = fmaxf(fminf(pb, tb) - fmaxf(pt, tt), 0.f);
                float inter = iw * ih;
                float uni = parea + b.z * b.w - inter;
                float iou = inter / fmaxf(uni, 1e-9f);
                maxiou = fmaxf(maxiou, iou);
            }
            if (ispos)              conf = bce_logits(rc, 1.f);
            else if (maxiou < 0.5f) conf = bce_logits(rc, 0.f);
        }

        for (int off = 32; off > 0; off >>= 1) conf += __shfl_down(conf, off);
        __shared__ float sc[4];
        if (lane == 0) sc[wid] = conf;
        __syncthreads();
        if (threadIdx.x == 0)
            partial[1 * 1024 + blockIdx.x] = sc[0] + sc[1] + sc[2] + sc[3];

    } else {
        // ---- positives: one wave per box ----
        int pb = blockIdx.x - NBLK;          // 0..47 = (level, image)
        int level = pb / NIMG;
        int n = pb % NIMG;
        const float *f, *lab;
        int W, HW; float stride;
        if (level == 0)      { f = f0; lab = l0; W = 52; HW = 52 * 52; stride = 8.f; }
        else if (level == 1) { f = f1; lab = l1; W = 26; HW = 26 * 26; stride = 16.f; }
        else                 { f = f2; lab = l2; W = 13; HW = 13 * 13; stride = 32.f; }

        int m = counts[pb];
        if (m > MAXB) m = MAXB;
        int bbase = pb * MAXB;

        float reg_acc = 0.f, prob_acc = 0.f;
        for (int i = wid; i < m; i += 4) {   // one wave per positive box
            int cell = cellids[bbase + i];   // (n*HW + hw)*3 + a
            float4 b = boxes[bbase + i];
            int a = cell % 3;
            int hw = (cell / 3) % HW;
            int w = hw % W;
            int h = hw / W;
            const float* fp = f + ((size_t)n * 255 + (size_t)a * 85) * HW + hw;
            const float* lp = lab + (size_t)cell * 85;

            // lanes 0..39: prob ch (5+lane) & (45+lane); lanes 40..43: raw xy/wh
            int ch1 = (lane < 40) ? (5 + lane) : ((lane < 44) ? (lane - 40) : 0);
            float g1 = fp[(size_t)ch1 * HW];                             // gather 1
            float g2 = fp[(size_t)((lane < 40) ? (45 + lane) : 0) * HW]; // gather 2
            float t1 = lp[(lane < 40) ? (5 + lane) : 0];
            float t2 = lp[(lane < 40) ? (45 + lane) : 0];

            float pp = (lane < 40) ? (bce_logits(g1, t1) + bce_logits(g2, t2)) : 0.f;
            for (int off = 32; off > 0; off >>= 1) pp += __shfl_down(pp, off);

            float rx = __shfl(g1, 40);
            float ry = __shfl(g1, 41);
            float rw = __shfl(g1, 42);
            float rh = __shfl(g1, 43);
            if (lane == 0) {
                prob_acc += pp;
                float aw = d_anchors[level][a][0];
                float ah = d_anchors[level][a][1];
                float ox = b.x / stride - (float)w;
                float oy = b.y / stride - (float)h;
                float ow = logf(b.z / aw + 1e-7f);
                float oh = logf(b.w / ah + 1e-7f);
                float scale = 2.f - b.z * b.w * (1.f / (416.f * 416.f));
                float dw = rw - ow, dh = rh - oh;
                reg_acc += scale * (bce_logits(rx, ox) + bce_logits(ry, oy))
                         + scale * 0.5f * (dw * dw + dh * dh);
            }
        }

        __shared__ float sp[2][4];
        if (lane == 0) { sp[0][wid] = reg_acc; sp[1][wid] = prob_acc; }
        __syncthreads();
        if (threadIdx.x == 0) {
            partial[0 * 1024 + pb] = sp[0][0] + sp[0][1] + sp[0][2] + sp[0][3];
            partial[2 * 1024 + pb] = sp[1][0] + sp[1][1] + sp[1][2] + sp[1][3];
        }
    }
}

// ---------------- Kernel C: finalize (1 block) ----------------
__global__ void finalize(const float* __restrict__ partial,
                         float* __restrict__ out) {
    float a0 = 0.f, a1 = 0.f, a2 = 0.f;
    for (int i = threadIdx.x; i < NBLK; i += 256) {
        a1 += partial[1 * 1024 + i];
        if (i < 48) {
            a0 += partial[0 * 1024 + i];
            a2 += partial[2 * 1024 + i];
        }
    }
    for (int off = 32; off > 0; off >>= 1) {
        a0 += __shfl_down(a0, off);
        a1 += __shfl_down(a1, off);
        a2 += __shfl_down(a2, off);
    }
    __shared__ float s[3][4];
    int lane = threadIdx.x & 63;
    int wid = threadIdx.x >> 6;
    if (lane == 0) { s[0][wid] = a0; s[1][wid] = a1; s[2][wid] = a2; }
    __syncthreads();
    if (threadIdx.x == 0) {
        out[0] = (s[0][0] + s[0][1] + s[0][2] + s[0][3]) * (1.f / 16.f);
        out[1] = (s[1][0] + s[1][1] + s[1][2] + s[1][3]) * (1.f / 16.f);
        out[2] = (s[2][0] + s[2][1] + s[2][2] + s[2][3]) * (1.f / 16.f);
    }
}

extern "C" void kernel_launch(void* const* d_in, const int* in_sizes, int n_in,
                              void* d_out, int out_size, void* d_ws, size_t ws_size,
                              hipStream_t stream) {
    const float* f0 = (const float*)d_in[0];
    const float* f1 = (const float*)d_in[1];
    const float* f2 = (const float*)d_in[2];
    const float* l0 = (const float*)d_in[3];
    const float* l1 = (const float*)d_in[4];
    const float* l2 = (const float*)d_in[5];
    float* out = (float*)d_out;

    int*    counts  = (int*)((char*)d_ws + WS_COUNTS);
    float4* boxes   = (float4*)((char*)d_ws + WS_BOXES);
    int*    cellids = (int*)((char*)d_ws + WS_CELLIDS);
    float*  partial = (float*)((char*)d_ws + WS_PARTIAL);

    hipMemsetAsync(d_ws, 0, 256, stream);   // zero counts

    scan_labels<<<NBLK, 256, 0, stream>>>(l0, l1, l2, counts, boxes, cellids);
    loss_fused<<<NBLK + 48, 256, 0, stream>>>(f0, f1, f2, l0, l1, l2,
                                              counts, boxes, cellids, partial);
    finalize<<<1, 256, 0, stream>>>(partial, out);
}